// Round 1
// baseline (545.513 us; speedup 1.0000x reference)
//
#include <hip/hip_runtime.h>
#include <math.h>

// Problem constants (fixed by reference file)
#define B_DIM    16
#define D_DIM    1024
#define K_FREQ   64          // frequencies; 2K = 128 features
#define F_DIM    128
#define N_MAXLEN 8192

#define BM   128             // m rows per block (4 waves x 32 rows)
#define LDSS 136             // padded W row stride in shorts (272 B -> 2-way bank = free)
#define TILE_SHORTS (128 * LDSS)   // one 128-row W tile: 17408 shorts = 34816 B

typedef __attribute__((ext_vector_type(8))) short bf16x8;   // MFMA A/B frag (4 VGPRs)
typedef __attribute__((ext_vector_type(4))) float f32x4;    // MFMA C/D frag

__device__ __forceinline__ unsigned f2bf(float x) {
    union { float f; unsigned u; } v; v.f = x;
    return (v.u + 0x7FFFu + ((v.u >> 16) & 1u)) >> 16;      // RNE
}

__device__ __forceinline__ void gload_lds16(const void* g, void* l) {
    __builtin_amdgcn_global_load_lds(
        (const __attribute__((address_space(1))) void*)g,
        (__attribute__((address_space(3))) void*)l, 16, 0, 0);
}

// Prologue: W fp32 [1024][128] -> bf16 [1024][LDSS] (pad baked in) in workspace,
// and the mask output. 128 blocks x 256 threads; each thread: one float4 of W
// + 4 mask entries.
__global__ __launch_bounds__(256) void prep_kernel(
    const int* __restrict__ lengths,
    const float* __restrict__ W,
    short* __restrict__ Wb,
    float* __restrict__ maskp)
{
    const int i = blockIdx.x * 256 + threadIdx.x;   // 0..32767
    const float4 w = ((const float4*)W)[i];
    const int row = i >> 5;                          // 32 float4 per 128-wide row
    const int c4  = i & 31;
    unsigned* p = (unsigned*)&Wb[row * LDSS + c4 * 4];
    p[0] = f2bf(w.x) | (f2bf(w.y) << 16);
    p[1] = f2bf(w.z) | (f2bf(w.w) << 16);

    const int m4  = i << 2;                          // 4 mask entries per thread
    const int b   = m4 >> 13;
    const int n   = m4 & (N_MAXLEN - 1);
    const int len = lengths[b];
    float4 mv;
    mv.x = (n     < len) ? 1.f : 0.f;
    mv.y = (n + 1 < len) ? 1.f : 0.f;
    mv.z = (n + 2 < len) ? 1.f : 0.f;
    mv.w = (n + 3 < len) ? 1.f : 0.f;
    ((float4*)maskp)[i] = mv;
}

// Main: grid = 1024 blocks over m. Each block: feats A-frags in registers
// (computed once), then loops 8 W d-tiles staged via global_load_lds.
// out[m][d] = sum_f feats[m][f] * W[d][f]
__global__ __launch_bounds__(256, 3) void cyclic_gemm_kernel(
    const int* __restrict__ lengths,
    const short* __restrict__ Wb,     // [1024][LDSS] bf16, pad baked in
    float* __restrict__ out)          // [B*N][D_DIM] fp32
{
    __shared__ short sB[TILE_SHORTS];

    const int tid  = threadIdx.x;
    const int lane = tid & 63;
    const int wave = tid >> 6;
    const int lrow = lane & 15;
    const int quad = lane >> 4;
    const int m0   = blockIdx.x * BM;
    const int b    = m0 >> 13;
    const int n0   = m0 & (N_MAXLEN - 1);
    const int len  = lengths[b];

    // ---- Fast path: fully masked block -> pure zero fill (no sincos/W/barriers)
    if (n0 >= len) {
        const float4 z = {0.f, 0.f, 0.f, 0.f};
        float4* p = (float4*)(out + (size_t)m0 * D_DIM);
        #pragma unroll 8
        for (int i = tid; i < BM * D_DIM / 4; i += 256) p[i] = z;
        return;
    }

    // ---- Stage W tile 0 early; its latency hides under the sincos below.
    {
        const short* Wt = Wb;
        #pragma unroll
        for (int i = 0; i < 8; ++i) {
            const int cb = i * 256 + wave * 64;      // chunk base (wave-uniform)
            gload_lds16(Wt + (size_t)(cb + lane) * 8, sB + (size_t)cb * 8);
        }
        if (wave < 2) {                              // tail 128 chunks
            const int cb = 2048 + wave * 64;
            gload_lds16(Wt + (size_t)(cb + lane) * 8, sB + (size_t)cb * 8);
        }
    }

    // ---- A fragments (feats) directly in registers: 32 sincos/thread, once.
    // af[mi][ks] element j: f = ks*32 + quad*8 + j ; k = f>>1 ; cos if j even.
    bf16x8 af[2][4];
    #pragma unroll
    for (int mi = 0; mi < 2; ++mi) {
        const int n = n0 + wave * 32 + mi * 16 + lrow;
        if (n >= len) {
            #pragma unroll
            for (int ks = 0; ks < 4; ++ks)
                af[mi][ks] = (bf16x8){0,0,0,0,0,0,0,0};
        } else {
            const float base = (float)n / (float)len;   // revolutions per unit freq
            #pragma unroll
            for (int ks = 0; ks < 4; ++ks) {
                #pragma unroll
                for (int jj = 0; jj < 4; ++jj) {
                    const int k = ks * 16 + quad * 4 + jj;  // freq index -> (k+1)
                    float rev = base * (float)(k + 1);
                    rev -= floorf(rev);                     // range-reduce to [0,1)
                    float s, c;
                    __sincosf(6.283185307179586f * rev, &s, &c);
                    af[mi][ks][2*jj]     = (short)f2bf(c * 0.125f);
                    af[mi][ks][2*jj + 1] = (short)f2bf(s * 0.125f);
                }
            }
        }
    }

    // ---- Loop the 8 d-tiles; A stays in registers across all of them.
    #pragma unroll 1
    for (int t = 0; t < 8; ++t) {
        __syncthreads();    // tile t landed (barrier drains vmcnt incl. load_lds)

        f32x4 acc[2][8];
        #pragma unroll
        for (int mi = 0; mi < 2; ++mi)
            #pragma unroll
            for (int ni = 0; ni < 8; ++ni)
                acc[mi][ni] = (f32x4){0.f, 0.f, 0.f, 0.f};

        #pragma unroll
        for (int ks = 0; ks < 4; ++ks) {            // K = 128 in 4 steps of 32
            bf16x8 bfr[8];
            #pragma unroll
            for (int ni = 0; ni < 8; ++ni)
                bfr[ni] = *(const bf16x8*)&sB[(ni*16 + lrow) * LDSS + ks*32 + quad*8];
            // Swapped operands: C row = d (reg-consecutive!), C col = m.
            #pragma unroll
            for (int mi = 0; mi < 2; ++mi)
                #pragma unroll
                for (int ni = 0; ni < 8; ++ni)
                    acc[mi][ni] = __builtin_amdgcn_mfma_f32_16x16x32_bf16(
                        bfr[ni], af[mi][ks], acc[mi][ni], 0, 0, 0);
        }

        // Stage next tile before the stores so loads fly under them.
        if (t < 7) {
            __syncthreads();  // all waves done reading sB for tile t
            const short* Wt = Wb + (size_t)(t + 1) * TILE_SHORTS;
            #pragma unroll
            for (int i = 0; i < 8; ++i) {
                const int cb = i * 256 + wave * 64;
                gload_lds16(Wt + (size_t)(cb + lane) * 8, sB + (size_t)cb * 8);
            }
            if (wave < 2) {
                const int cb = 2048 + wave * 64;
                gload_lds16(Wt + (size_t)(cb + lane) * 8, sB + (size_t)cb * 8);
            }
        }

        // ---- Epilogue: float4 stores, d = t*128 + ni*16 + quad*4 + reg.
        const int d0 = t * 128;
        #pragma unroll
        for (int mi = 0; mi < 2; ++mi) {
            const int m = m0 + wave * 32 + mi * 16 + lrow;
            float* orow = out + (size_t)m * D_DIM + d0 + quad * 4;
            #pragma unroll
            for (int ni = 0; ni < 8; ++ni)
                *(float4*)(orow + ni * 16) = *(float4*)&acc[mi][ni];
        }
    }
}

extern "C" void kernel_launch(void* const* d_in, const int* in_sizes, int n_in,
                              void* d_out, int out_size, void* d_ws, size_t ws_size,
                              hipStream_t stream) {
    const int*   lengths = (const int*)d_in[0];
    const float* W       = (const float*)d_in[1];
    // d_in[2] is N_max (== 8192), compile-time constant here.
    float* out   = (float*)d_out;
    float* maskp = out + (size_t)B_DIM * N_MAXLEN * D_DIM;
    short* Wb    = (short*)d_ws;                    // 1024*136*2 = 278,528 B

    prep_kernel<<<dim3(128), dim3(256), 0, stream>>>(lengths, W, Wb, maskp);

    dim3 grid((B_DIM * N_MAXLEN) / BM);             // 1024 blocks over m
    cyclic_gemm_kernel<<<grid, dim3(256), 0, stream>>>(lengths, Wb, out);
}